// Round 12
// baseline (517.947 us; speedup 1.0000x reference)
//
#include <hip/hip_runtime.h>

#define N_NODES 50000
#define N_EDGES 800000
#define DIM 128
#define N_GRAPHS 256
#define N_CLS 10
#define BN_EPSV 1e-5f
#define CAP 64
#define RSIZE 6250  // N_NODES / 8
#define NBLK ((N_NODES + 63) / 64)
#define ZROW N_NODES              // index of the all-zero feature row
#define SLICE ((N_NODES + 1) * 16)  // ushorts per 16-col slice region
#define AGG_WPC 768               // aggregation waves per class (192 blk x 4)

typedef __attribute__((ext_vector_type(8))) short short8;
typedef __attribute__((ext_vector_type(4))) float f32x4;

__device__ __forceinline__ float bf2f(short u) {
  return __uint_as_float(((unsigned)(unsigned short)u) << 16);
}
__device__ __forceinline__ unsigned short f2bf(float f) {
  unsigned u = __float_as_uint(f);
  unsigned r = (u + 0x7FFFu + ((u >> 16) & 1u)) >> 16;
  return (unsigned short)r;
}
// XOR swizzle: spreads row-major [64][128]-bf16 rows across banks for ds_read_b128
__device__ __forceinline__ int swz(int row, int bytecol) {
  return row * 256 + (bytecol ^ ((row & 7) << 4));
}

// ---------------- prep: cvt_w | cvt_x->slice-major | bounds+cnt0 | zero-rows -

__global__ __launch_bounds__(256) void prep_kernel(
    const float* __restrict__ x, ushort* __restrict__ xb,
    const float* __restrict__ w0, const float* __restrict__ w1,
    const float* __restrict__ w2, const float* __restrict__ w3,
    const float* __restrict__ w4, const float* __restrict__ w5,
    ushort* __restrict__ wt, const int* __restrict__ batch,
    int* __restrict__ gstart, int* __restrict__ cnt,
    ushort* __restrict__ z0, ushort* __restrict__ z1) {
  int bid = blockIdx.x, tid = threadIdx.x;
  if (bid < 384) {
    // W (fan_in x fan_out) fp32 -> W^T bf16, 6 matrices
    int m = bid >> 6;
    const float* w = m == 0 ? w0 : m == 1 ? w1 : m == 2 ? w2 : m == 3 ? w3
                                                         : m == 4 ? w4 : w5;
    int idx = (bid & 63) * 256 + tid;
    int k = idx >> 7, n = idx & 127;
    wt[m * 16384 + n * 128 + k] = f2bf(w[idx]);
  } else if (bid < 384 + 3125) {
    // x (node-major fp32) -> xb (slice-major bf16): task = (s, node, half)
    int id = (bid - 384) * 256 + tid;
    if (id < 8 * N_NODES * 2) {
      int s = id / (N_NODES * 2);
      int r = id - s * (N_NODES * 2);
      int node = r >> 1, h = r & 1;
      const float* src = x + (size_t)node * DIM + s * 16 + h * 8;
      float4 a = *(const float4*)src;
      float4 b = *(const float4*)(src + 4);
      short8 o;
      o[0] = (short)f2bf(a.x); o[1] = (short)f2bf(a.y);
      o[2] = (short)f2bf(a.z); o[3] = (short)f2bf(a.w);
      o[4] = (short)f2bf(b.x); o[5] = (short)f2bf(b.y);
      o[6] = (short)f2bf(b.z); o[7] = (short)f2bf(b.w);
      *(short8*)(xb + (size_t)s * SLICE + node * 16 + h * 8) = o;
    }
  } else if (bid < 384 + 3125 + 196) {
    int i = (bid - (384 + 3125)) * 256 + tid;
    if (i < N_NODES) {
      cnt[i] = 0;
      int b = batch[i];
      int prev = (i == 0) ? -1 : batch[i - 1];
      for (int g = prev + 1; g <= b; g++) gstart[g] = i;
      if (i == N_NODES - 1)
        for (int g = b + 1; g <= N_GRAPHS; g++) gstart[g] = N_NODES;
    }
  } else {
    // zero row per slice in both feature buffers
    if (tid < 128) {
      int s = tid >> 4, cc = tid & 15;
      z0[(size_t)s * SLICE + (size_t)ZROW * 16 + cc] = 0;
      z1[(size_t)s * SLICE + (size_t)ZROW * 16 + cc] = 0;
    }
  }
}

// ---------------- CSR build: XCD-affine range partition ---------------------

__global__ __launch_bounds__(256) void fill_kernel(
    const int* __restrict__ src, const int* __restrict__ dst,
    int* __restrict__ cnt, ushort* __restrict__ csr) {
  int cls = blockIdx.x & 7;
  int lo = cls * RSIZE;
  int hi = lo + RSIZE;
  int i = (blockIdx.x >> 3) * blockDim.x + threadIdx.x;
  int stride = (gridDim.x >> 3) * blockDim.x;
  for (; i < N_EDGES; i += stride) {
    int d = dst[i];
    if (d >= lo && d < hi) {
      int p = atomicAdd(&cnt[d], 1);
      if (p < CAP) csr[(size_t)d * CAP + p] = (ushort)src[i];
    }
  }
}

// ---------------- sliced aggregation: class c (XCD c) does 16-col slice c ---
// Each XCD's slice (1.6MB) is L2-resident -> the 205MB logical gather runs at
// L2-hit bandwidth. Wave: 16 neighbor slots x 4 col-quads; ILP-4 over nodes.
// Invalid slots -> ZROW (zero row). Prev-layer BN folded as per-col affine.

template <bool FIRST>
__global__ __launch_bounds__(256, 6) void agg_kernel(
    const ushort* __restrict__ xin, const int* __restrict__ cnt,
    const ushort* __restrict__ csr, const float* __restrict__ pstats,
    const float* __restrict__ pgamma, const float* __restrict__ pbeta,
    const float* __restrict__ epsp, int layer, ushort* __restrict__ agg) {
  int c = blockIdx.x & 7;
  int wv = (blockIdx.x >> 3) * 4 + (threadIdx.x >> 6);  // 0..AGG_WPC-1
  int l = threadIdx.x & 63;
  int slot = l >> 2, colq = l & 3;
  const ushort* F = xin + (size_t)c * SLICE;
  ushort* A = agg + (size_t)c * SLICE;
  float epv = 1.0f + epsp[layer];
  float sc4[4], sh4[4];
  if (!FIRST) {
    const float invN = 1.0f / N_NODES;
#pragma unroll
    for (int j = 0; j < 4; j++) {
      int col = c * 16 + colq * 4 + j;
      float mu = pstats[col] * invN;
      float var = fmaxf(pstats[DIM + col] * invN - mu * mu, 0.f);
      float s = pgamma[col] * rsqrtf(var + BN_EPSV);
      sc4[j] = s;
      sh4[j] = pbeta[col] - mu * s;
    }
  }
  for (int nb0 = wv; nb0 < N_NODES; nb0 += AGG_WPC * 4) {
    int n_[4], d_[4];
#pragma unroll
    for (int q = 0; q < 4; q++) {
      n_[q] = nb0 + AGG_WPC * q;
      int valid = n_[q] < N_NODES;
      int ndc = valid ? n_[q] : 0;
      int dd = cnt[ndc];
      dd = dd < CAP ? dd : CAP;
      d_[q] = valid ? dd : 0;
    }
    int dmax = max(max(d_[0], d_[1]), max(d_[2], d_[3]));
    int nbat = (dmax + 15) >> 4;
    float av[4][4];
#pragma unroll
    for (int q = 0; q < 4; q++)
#pragma unroll
      for (int j = 0; j < 4; j++) av[q][j] = 0.f;
    for (int b = 0; b < nbat; b++) {
      int si = b * 16 + slot;
#pragma unroll
      for (int q = 0; q < 4; q++) {
        int ndc = n_[q] < N_NODES ? n_[q] : 0;
        int e = csr[(size_t)ndc * CAP + (si < d_[q] ? si : 0)];
        int j = si < d_[q] ? e : ZROW;
        ushort4 p = *(const ushort4*)(F + j * 16 + colq * 4);
        av[q][0] += bf2f((short)p.x);
        av[q][1] += bf2f((short)p.y);
        av[q][2] += bf2f((short)p.z);
        av[q][3] += bf2f((short)p.w);
      }
    }
#pragma unroll
    for (int q = 0; q < 4; q++)
#pragma unroll
      for (int j = 0; j < 4; j++) {
        av[q][j] += __shfl_xor(av[q][j], 4, 64);
        av[q][j] += __shfl_xor(av[q][j], 8, 64);
        av[q][j] += __shfl_xor(av[q][j], 16, 64);
        av[q][j] += __shfl_xor(av[q][j], 32, 64);
      }
    if (slot == 0) {  // lanes 0..3 hold the 16-col slice sums
#pragma unroll
      for (int q = 0; q < 4; q++) {
        if (n_[q] >= N_NODES) continue;
        ushort4 sv = *(const ushort4*)(F + n_[q] * 16 + colq * 4);
        float o0 = epv * bf2f((short)sv.x) + av[q][0];
        float o1 = epv * bf2f((short)sv.y) + av[q][1];
        float o2 = epv * bf2f((short)sv.z) + av[q][2];
        float o3 = epv * bf2f((short)sv.w) + av[q][3];
        if (!FIRST) {
          float co = epv + (float)d_[q];
          o0 = sc4[0] * o0 + co * sh4[0];
          o1 = sc4[1] * o1 + co * sh4[1];
          o2 = sc4[2] * o2 + co * sh4[2];
          o3 = sc4[3] * o3 + co * sh4[3];
        }
        ushort4 ov;
        ov.x = f2bf(o0); ov.y = f2bf(o1); ov.z = f2bf(o2); ov.w = f2bf(o3);
        *(ushort4*)(A + n_[q] * 16 + colq * 4) = ov;
      }
    }
  }
}

// ---------------- MLP: h = relu(relu(agg@W1+b1)@W2+b2) + per-block stats ----
// Block = 64 nodes, 8 waves (512 thr). Stage-in/out slice-major (coalesced
// per-slice 2KB chunks). MFMA GEMMs from swizzled LDS; stats -> bstat.

__global__ __launch_bounds__(512, 8) void mlp_kernel(
    const ushort* __restrict__ agg, const ushort* __restrict__ W1T,
    const float* __restrict__ b1, const ushort* __restrict__ W2T,
    const float* __restrict__ b2, ushort* __restrict__ out,
    float* __restrict__ bstat) {
  __shared__ __align__(16) ushort As[64 * DIM];
  __shared__ __align__(16) ushort H1[64 * DIM];
  __shared__ float sums[8 * DIM];
  __shared__ float sqs[8 * DIM];
  int tid = threadIdx.x;
  int w8 = tid >> 6;
  int l = tid & 63, li = l & 15, lg = l >> 4;
  int row0 = blockIdx.x * 64;
  // stage-in: slice-major agg -> swizzled LDS (per-slice contiguous 2KB)
  for (int t = tid; t < 1024; t += 512) {
    int s = t >> 7, idx = t & 127;
    int nl = idx >> 1, h = idx & 1;
    int grow = row0 + nl;
    short8 v = {};
    if (grow < N_NODES)
      v = *(const short8*)(agg + (size_t)s * SLICE + grow * 16 + h * 8);
    *(short8*)((char*)As + swz(nl, s * 32 + h * 16)) = v;
  }
  __syncthreads();
  // ---- GEMM1: H1[rows wg][cts ch*4..] = relu(As @ W1 + b1) ----
  int wg = w8 >> 1;  // row group (16 rows)
  int ch = w8 & 1;   // column half
  {
    f32x4 acc[4] = {};
    short8 af[4];
#pragma unroll
    for (int ks = 0; ks < 4; ks++)
      af[ks] = *(const short8*)((char*)As + swz(16 * wg + li, ks * 64 + lg * 16));
#pragma unroll
    for (int ct4 = 0; ct4 < 4; ct4++) {
      int ct = ch * 4 + ct4;
      const char* wp = (const char*)W1T + (ct * 16 + li) * 256 + lg * 16;
#pragma unroll
      for (int ks = 0; ks < 4; ks++) {
        short8 bf = *(const short8*)(wp + ks * 64);
        acc[ct4] = __builtin_amdgcn_mfma_f32_16x16x32_bf16(af[ks], bf, acc[ct4], 0, 0, 0);
      }
    }
#pragma unroll
    for (int ct4 = 0; ct4 < 4; ct4++) {
      int ct = ch * 4 + ct4;
      float bv = b1[ct * 16 + li];
#pragma unroll
      for (int r = 0; r < 4; r++) {
        int row = 16 * wg + lg * 4 + r;
        *(ushort*)((char*)H1 + swz(row, (ct * 16 + li) * 2)) =
            f2bf(fmaxf(acc[ct4][r] + bv, 0.f));
      }
    }
  }
  __syncthreads();
  // ---- GEMM2: h2 = relu(H1 @ W2 + b2) -> staged LDS + partial stats ----
  float ss[4] = {0, 0, 0, 0}, sq[4] = {0, 0, 0, 0};
  {
    f32x4 acc[4] = {};
    short8 af[4];
#pragma unroll
    for (int ks = 0; ks < 4; ks++)
      af[ks] = *(const short8*)((char*)H1 + swz(16 * wg + li, ks * 64 + lg * 16));
#pragma unroll
    for (int ct4 = 0; ct4 < 4; ct4++) {
      int ct = ch * 4 + ct4;
      const char* wp = (const char*)W2T + (ct * 16 + li) * 256 + lg * 16;
#pragma unroll
      for (int ks = 0; ks < 4; ks++) {
        short8 bf = *(const short8*)(wp + ks * 64);
        acc[ct4] = __builtin_amdgcn_mfma_f32_16x16x32_bf16(af[ks], bf, acc[ct4], 0, 0, 0);
      }
    }
#pragma unroll
    for (int ct4 = 0; ct4 < 4; ct4++) {
      int ct = ch * 4 + ct4;
      float bv = b2[ct * 16 + li];
#pragma unroll
      for (int r = 0; r < 4; r++) {
        int row = 16 * wg + lg * 4 + r;
        float v = fmaxf(acc[ct4][r] + bv, 0.f);
        *(ushort*)((char*)As + swz(row, (ct * 16 + li) * 2)) = f2bf(v);
        float vm = (row0 + row < N_NODES) ? v : 0.f;
        ss[ct4] += vm;
        sq[ct4] += vm * vm;
      }
    }
  }
#pragma unroll
  for (int ct4 = 0; ct4 < 4; ct4++) {
    ss[ct4] += __shfl_xor(ss[ct4], 16, 64);
    ss[ct4] += __shfl_xor(ss[ct4], 32, 64);
    sq[ct4] += __shfl_xor(sq[ct4], 16, 64);
    sq[ct4] += __shfl_xor(sq[ct4], 32, 64);
  }
  if (l < 16) {
#pragma unroll
    for (int ct4 = 0; ct4 < 4; ct4++) {
      sums[w8 * DIM + (ch * 4 + ct4) * 16 + l] = ss[ct4];
      sqs[w8 * DIM + (ch * 4 + ct4) * 16 + l] = sq[ct4];
      sums[w8 * DIM + ((1 - ch) * 4 + ct4) * 16 + l] = 0.f;
      sqs[w8 * DIM + ((1 - ch) * 4 + ct4) * 16 + l] = 0.f;
    }
  }
  __syncthreads();
  // copy-out: swizzled LDS -> slice-major h2 (per-slice contiguous 2KB)
  for (int t = tid; t < 1024; t += 512) {
    int s = t >> 7, idx = t & 127;
    int nl = idx >> 1, h = idx & 1;
    int grow = row0 + nl;
    if (grow < N_NODES) {
      short8 v = *(const short8*)((char*)As + swz(nl, s * 32 + h * 16));
      *(short8*)(out + (size_t)s * SLICE + grow * 16 + h * 8) = v;
    }
  }
  if (tid < DIM) {
    float t1 = 0.f, t2 = 0.f;
#pragma unroll
    for (int g = 0; g < 8; g++) {
      t1 += sums[g * DIM + tid];
      t2 += sqs[g * DIM + tid];
    }
    bstat[(size_t)blockIdx.x * DIM + tid] = t1;
    bstat[((size_t)NBLK + blockIdx.x) * DIM + tid] = t2;
  }
}

// ---------------- stats reduce: 256 cols (sum | sumsq), shuffle-reduce ------

__global__ __launch_bounds__(64) void stats_reduce_kernel(
    const float* __restrict__ bstat, float* __restrict__ stats) {
  int c = blockIdx.x;
  int t = threadIdx.x;
  const float* src = bstat + (c < DIM ? 0 : (size_t)NBLK * DIM) + (c & (DIM - 1));
  float a = 0.f;
  for (int b = t; b < NBLK; b += 64) a += src[(size_t)b * DIM];
#pragma unroll
  for (int m = 32; m >= 1; m >>= 1) a += __shfl_xor(a, m, 64);
  if (t == 0) stats[c] = a;
}

// ---------------- pooling: one block per graph, slice-major h ---------------

__global__ __launch_bounds__(128) void pool2_kernel(const ushort* __restrict__ h,
    const int* __restrict__ gstart, float* __restrict__ pool) {
  int g = blockIdx.x, t = threadIdx.x;
  int s = t >> 4, cc = t & 15;
  const ushort* H = h + (size_t)s * SLICE + cc;
  int st = gstart[g], e = gstart[g + 1];
  float a0 = 0.f, a1 = 0.f, a2 = 0.f, a3 = 0.f;
  int i = st;
  for (; i + 3 < e; i += 4) {
    a0 += bf2f((short)H[(i + 0) * 16]);
    a1 += bf2f((short)H[(i + 1) * 16]);
    a2 += bf2f((short)H[(i + 2) * 16]);
    a3 += bf2f((short)H[(i + 3) * 16]);
  }
  for (; i < e; i++) a0 += bf2f((short)H[i * 16]);
  float cn = (float)(e - st);
  if (cn < 1.f) cn = 1.f;
  pool[g * DIM + t] = ((a0 + a1) + (a2 + a3)) / cn;
}

// ---------------- final: BN affine (layer 3) + MLP + log_softmax -----------

__global__ __launch_bounds__(128) void final_kernel(const float* __restrict__ pool,
    const float* __restrict__ stats3,
    const float* __restrict__ gamma3, const float* __restrict__ beta3,
    const float* __restrict__ lw1, const float* __restrict__ lb1,
    const float* __restrict__ lw2, const float* __restrict__ lb2,
    float* __restrict__ out) {
  int g = blockIdx.x, t = threadIdx.x;
  __shared__ float p[DIM];
  __shared__ float part[2];
  __shared__ float z2[N_CLS];
  const float invN = 1.0f / N_NODES;
  float mu = stats3[t] * invN;
  float var = fmaxf(stats3[DIM + t] * invN - mu * mu, 0.f);
  float sc = gamma3[t] * rsqrtf(var + BN_EPSV);
  float sh = beta3[t] - mu * sc;
  p[t] = sc * pool[g * DIM + t] + sh;
  __syncthreads();
  float acc = lb1[t];
  for (int k = 0; k < DIM; k++) acc += p[k] * lw1[k * DIM + t];
  acc = fmaxf(acc, 0.f);
  for (int c = 0; c < N_CLS; c++) {
    float v = acc * lw2[t * N_CLS + c];
#pragma unroll
    for (int m = 32; m >= 1; m >>= 1) v += __shfl_xor(v, m, 64);
    if ((t & 63) == 0) part[t >> 6] = v;
    __syncthreads();
    if (t == 0) z2[c] = part[0] + part[1] + lb2[c];
    __syncthreads();
  }
  if (t == 0) {
    float mx = -1e30f;
    for (int c = 0; c < N_CLS; c++) mx = fmaxf(mx, z2[c]);
    float sum = 0.f;
    for (int c = 0; c < N_CLS; c++) sum += expf(z2[c] - mx);
    float lse = mx + logf(sum);
    for (int c = 0; c < N_CLS; c++) out[g * N_CLS + c] = z2[c] - lse;
  }
}

// ---------------- launch ----------------

extern "C" void kernel_launch(void* const* d_in, const int* in_sizes, int n_in,
                              void* d_out, int out_size, void* d_ws, size_t ws_size,
                              hipStream_t stream) {
  const float* x = (const float*)d_in[0];
  const int* edge = (const int*)d_in[1];
  const int* batch = (const int*)d_in[2];
  const float *w[3][2], *bv[3][2], *gam[3], *bet[3];
  int idx = 3;
  for (int l = 0; l < 3; l++) {
    w[l][0] = (const float*)d_in[idx++]; bv[l][0] = (const float*)d_in[idx++];
    w[l][1] = (const float*)d_in[idx++]; bv[l][1] = (const float*)d_in[idx++];
    gam[l] = (const float*)d_in[idx++];  bet[l] = (const float*)d_in[idx++];
  }
  const float* eps = (const float*)d_in[idx++];
  const float* lw1 = (const float*)d_in[idx++];
  const float* lb1 = (const float*)d_in[idx++];
  const float* lw2 = (const float*)d_in[idx++];
  const float* lb2 = (const float*)d_in[idx++];

  char* ws = (char*)d_ws;
  size_t off_b = 0;
  auto alloc = [&](size_t b) -> char* {
    char* p = ws + off_b;
    off_b += (b + 255) & ~(size_t)255;
    return p;
  };
  int* cnt = (int*)alloc((size_t)N_NODES * 4);
  ushort* csr = (ushort*)alloc((size_t)N_NODES * CAP * 2);
  ushort* P0 = (ushort*)alloc((size_t)8 * SLICE * 2);  // slice-major features
  ushort* P1 = (ushort*)alloc((size_t)8 * SLICE * 2);
  ushort* aggb = (ushort*)alloc((size_t)8 * SLICE * 2);
  ushort* wt = (ushort*)alloc((size_t)6 * 16384 * 2);
  float* stats = (float*)alloc(3 * 2 * DIM * 4);
  float* pool = (float*)alloc((size_t)N_GRAPHS * DIM * 4);
  int* gstart = (int*)alloc((size_t)(N_GRAPHS + 1) * 4);
  float* bstat = (float*)alloc((size_t)2 * NBLK * DIM * 4);

  const int* srcp = edge;
  const int* dstp = edge + N_EDGES;
  // prep: cvt_w (384) | cvt_x slice-major (3125) | bounds+cnt0 (196) | zeros (1)
  prep_kernel<<<384 + 3125 + 196 + 1, 256, 0, stream>>>(
      x, P0, w[0][0], w[0][1], w[1][0], w[1][1], w[2][0], w[2][1], wt,
      batch, gstart, cnt, P0, P1);
  fill_kernel<<<2048, 256, 0, stream>>>(srcp, dstp, cnt, csr);

  // L1: agg(P0)->aggb, mlp(aggb)->P1
  agg_kernel<true><<<1536, 256, 0, stream>>>(
      P0, cnt, csr, nullptr, nullptr, nullptr, eps, 0, aggb);
  mlp_kernel<<<NBLK, 512, 0, stream>>>(aggb, wt + 0 * 16384, bv[0][0],
                                       wt + 1 * 16384, bv[0][1], P1, bstat);
  stats_reduce_kernel<<<256, 64, 0, stream>>>(bstat, stats);
  // L2: agg(P1, fold s0)->aggb, mlp->P0
  agg_kernel<false><<<1536, 256, 0, stream>>>(
      P1, cnt, csr, stats, gam[0], bet[0], eps, 1, aggb);
  mlp_kernel<<<NBLK, 512, 0, stream>>>(aggb, wt + 2 * 16384, bv[1][0],
                                       wt + 3 * 16384, bv[1][1], P0, bstat);
  stats_reduce_kernel<<<256, 64, 0, stream>>>(bstat, stats + 2 * DIM);
  // L3: agg(P0, fold s1)->aggb, mlp->P1
  agg_kernel<false><<<1536, 256, 0, stream>>>(
      P0, cnt, csr, stats + 2 * DIM, gam[1], bet[1], eps, 2, aggb);
  mlp_kernel<<<NBLK, 512, 0, stream>>>(aggb, wt + 4 * 16384, bv[2][0],
                                       wt + 5 * 16384, bv[2][1], P1, bstat);
  stats_reduce_kernel<<<256, 64, 0, stream>>>(bstat, stats + 4 * DIM);

  pool2_kernel<<<N_GRAPHS, 128, 0, stream>>>(P1, gstart, pool);
  final_kernel<<<N_GRAPHS, 128, 0, stream>>>(pool, stats + 4 * DIM,
                                             gam[2], bet[2], lw1, lb1, lw2, lb2,
                                             (float*)d_out);
}

// Round 13
// 275.824 us; speedup vs baseline: 1.8778x; 1.8778x over previous
//
#include <hip/hip_runtime.h>

#define N_NODES 50000
#define N_EDGES 800000
#define DIM 128
#define N_GRAPHS 256
#define N_CLS 10
#define BN_EPSV 1e-5f
#define CAP 64
#define RSIZE 6250  // N_NODES / 8
#define NBLK32 ((N_NODES + 31) / 32)
#define ZROW N_NODES  // index of the all-zero feature row

typedef __attribute__((ext_vector_type(8))) short short8;
typedef __attribute__((ext_vector_type(4))) float f32x4;

__device__ __forceinline__ float bf2f(short u) {
  return __uint_as_float(((unsigned)(unsigned short)u) << 16);
}
__device__ __forceinline__ unsigned short f2bf(float f) {
  unsigned u = __float_as_uint(f);
  unsigned r = (u + 0x7FFFu + ((u >> 16) & 1u)) >> 16;
  return (unsigned short)r;
}
// XOR swizzle: spreads row-major [32][128]-bf16 rows across banks for ds_read_b128
__device__ __forceinline__ int swz(int row, int bytecol) {
  return row * 256 + (bytecol ^ ((row & 7) << 4));
}

// ---------------- prep: cvt_w | cvt_x | bounds+cnt-zero | zero-rows ---------

__global__ __launch_bounds__(256) void prep_kernel(
    const float* __restrict__ x, ushort* __restrict__ xb,
    const float* __restrict__ w0, const float* __restrict__ w1,
    const float* __restrict__ w2, const float* __restrict__ w3,
    const float* __restrict__ w4, const float* __restrict__ w5,
    ushort* __restrict__ wt, const int* __restrict__ batch,
    int* __restrict__ gstart, int* __restrict__ cnt,
    ushort* __restrict__ z0, ushort* __restrict__ z1) {
  int bid = blockIdx.x, tid = threadIdx.x;
  if (bid < 384) {
    // W (fan_in x fan_out) fp32 -> W^T bf16, 6 matrices
    int m = bid >> 6;
    const float* w = m == 0 ? w0 : m == 1 ? w1 : m == 2 ? w2 : m == 3 ? w3
                                                         : m == 4 ? w4 : w5;
    int idx = (bid & 63) * 256 + tid;
    int k = idx >> 7, n = idx & 127;
    wt[m * 16384 + n * 128 + k] = f2bf(w[idx]);
  } else if (bid < 384 + 2048) {
    const int tot = N_NODES * DIM / 4;
    int i = (bid - 384) * 256 + tid;
    for (; i < tot; i += 2048 * 256) {
      float4 v = ((const float4*)x)[i];
      ushort4 o;
      o.x = f2bf(v.x); o.y = f2bf(v.y); o.z = f2bf(v.z); o.w = f2bf(v.w);
      ((ushort4*)xb)[i] = o;
    }
  } else if (bid < 384 + 2048 + 196) {
    int i = (bid - (384 + 2048)) * 256 + tid;
    if (i < N_NODES) {
      cnt[i] = 0;
      int b = batch[i];
      int prev = (i == 0) ? -1 : batch[i - 1];
      for (int g = prev + 1; g <= b; g++) gstart[g] = i;
      if (i == N_NODES - 1)
        for (int g = b + 1; g <= N_GRAPHS; g++) gstart[g] = N_NODES;
    }
  } else {
    if (tid < DIM) {
      z0[(size_t)ZROW * DIM + tid] = 0;
      z1[(size_t)ZROW * DIM + tid] = 0;
    }
  }
}

// ---------------- CSR build: XCD-affine range partition ---------------------

__global__ __launch_bounds__(256) void fill_kernel(
    const int* __restrict__ src, const int* __restrict__ dst,
    int* __restrict__ cnt, ushort* __restrict__ csr) {
  int cls = blockIdx.x & 7;
  int lo = cls * RSIZE;
  int hi = lo + RSIZE;
  int i = (blockIdx.x >> 3) * blockDim.x + threadIdx.x;
  int stride = (gridDim.x >> 3) * blockDim.x;
  for (; i < N_EDGES; i += stride) {
    int d = dst[i];
    if (d >= lo && d < hi) {
      int p = atomicAdd(&cnt[d], 1);
      if (p < CAP) csr[(size_t)d * CAP + p] = (ushort)src[i];
    }
  }
}

// ---------------- fused layer: batched gather -> LDS -> 2x MFMA GEMM --------
// 256 thr / 4 waves / 32 nodes / 20KB LDS -> 8 blocks/CU (32 waves/CU),
// grid 1563 (6.1 blocks/CU): more independent L2-miss streams per CU and
// finer barrier granularity than the 64-node/512-thr tile (3.05 blocks/CU).
// Phase A: per node, neighbors in batches of 16 (4 per lane-group, 4 loads in
// flight); invalid slots redirect to the L2-hot all-zero row. BN sc/sh staged
// in phase-C-dead sums/sqs LDS. Phases B/C: MFMA GEMMs; stats -> bstat.

template <bool FIRST>
__global__ __launch_bounds__(256, 8) void layer_kernel(
    const ushort* __restrict__ xin, const int* __restrict__ cnt,
    const ushort* __restrict__ csr, const float* __restrict__ pstats,
    const float* __restrict__ pgamma, const float* __restrict__ pbeta,
    const float* __restrict__ epsp, int layer,
    const ushort* __restrict__ W1T, const float* __restrict__ b1,
    const ushort* __restrict__ W2T, const float* __restrict__ b2,
    ushort* __restrict__ out, float* __restrict__ bstat) {
  __shared__ __align__(16) ushort As[32 * DIM];
  __shared__ __align__(16) ushort H1[32 * DIM];
  __shared__ float sums[4 * DIM];
  __shared__ float sqs[4 * DIM];
  int tid = threadIdx.x;
  int w4 = tid >> 6;       // wave 0..3
  int l = tid & 63, li = l & 15, lg = l >> 4;
  int row0 = blockIdx.x * 32;
  float epv = 1.0f + epsp[layer];
  if (!FIRST) {
    // stage BN affine (sc, sh) into phase-C-dead LDS (saves 16 VGPRs)
    if (tid < DIM) {
      const float invN = 1.0f / N_NODES;
      float mu = pstats[tid] * invN;
      float var = fmaxf(pstats[DIM + tid] * invN - mu * mu, 0.f);
      float sc = pgamma[tid] * rsqrtf(var + BN_EPSV);
      sums[tid] = sc;
      sqs[tid] = pbeta[tid] - mu * sc;
    }
    __syncthreads();
  }
  // ---- Phase A: batched gather-aggregate into swizzled LDS ----
  for (int n = 0; n < 8; n++) {
    int nl = w4 * 8 + n;
    int node = row0 + nl;
    float av[8];
#pragma unroll
    for (int j = 0; j < 8; j++) av[j] = 0.f;
    if (node < N_NODES) {
      int deg = cnt[node];
      deg = deg < CAP ? deg : CAP;
      const ushort* nb = csr + (size_t)node * CAP;
      if (lg == 0) {
        short8 sv = *(const short8*)(xin + (size_t)node * DIM + li * 8);
#pragma unroll
        for (int j = 0; j < 8; j++) av[j] = epv * bf2f(sv[j]);
      }
      int nbat = (deg + 15) >> 4;
      for (int b = 0; b < nbat; b++) {
        int i0 = b * 16 + lg, i1 = i0 + 4, i2 = i0 + 8, i3 = i0 + 12;
        int r0 = nb[i0 < deg ? i0 : 0];
        int r1 = nb[i1 < deg ? i1 : 0];
        int r2 = nb[i2 < deg ? i2 : 0];
        int r3 = nb[i3 < deg ? i3 : 0];
        int j0 = i0 < deg ? r0 : ZROW;
        int j1 = i1 < deg ? r1 : ZROW;
        int j2 = i2 < deg ? r2 : ZROW;
        int j3 = i3 < deg ? r3 : ZROW;
        short8 v0 = *(const short8*)(xin + (size_t)j0 * DIM + li * 8);
        short8 v1 = *(const short8*)(xin + (size_t)j1 * DIM + li * 8);
        short8 v2 = *(const short8*)(xin + (size_t)j2 * DIM + li * 8);
        short8 v3 = *(const short8*)(xin + (size_t)j3 * DIM + li * 8);
#pragma unroll
        for (int j = 0; j < 8; j++)
          av[j] += (bf2f(v0[j]) + bf2f(v1[j])) + (bf2f(v2[j]) + bf2f(v3[j]));
      }
#pragma unroll
      for (int j = 0; j < 8; j++) {
        av[j] += __shfl_xor(av[j], 16, 64);
        av[j] += __shfl_xor(av[j], 32, 64);
      }
      if (!FIRST && lg == 0) {
        float co = epv + (float)deg;
#pragma unroll
        for (int j = 0; j < 8; j++)
          av[j] = sums[li * 8 + j] * av[j] + co * sqs[li * 8 + j];
      }
    }
    if (lg == 0) {
      short8 uv;
#pragma unroll
      for (int j = 0; j < 8; j++) uv[j] = (short)f2bf(av[j]);
      *(short8*)((char*)As + swz(nl, li * 16)) = uv;
    }
  }
  __syncthreads();
  // ---- Phase B: H1[rows wg][cts ch*4..] = relu(As @ W1 + b1) ----
  int wg = w4 >> 1;        // row group (16 rows each, 0..1)
  int ch = w4 & 1;         // column half: cts [ch*4, ch*4+3]
  {
    f32x4 acc[4] = {};
    short8 af[4];
#pragma unroll
    for (int ks = 0; ks < 4; ks++)
      af[ks] = *(const short8*)((char*)As + swz(16 * wg + li, ks * 64 + lg * 16));
#pragma unroll
    for (int ct4 = 0; ct4 < 4; ct4++) {
      int ct = ch * 4 + ct4;
      const char* wp = (const char*)W1T + (ct * 16 + li) * 256 + lg * 16;
#pragma unroll
      for (int ks = 0; ks < 4; ks++) {
        short8 bf = *(const short8*)(wp + ks * 64);
        acc[ct4] = __builtin_amdgcn_mfma_f32_16x16x32_bf16(af[ks], bf, acc[ct4], 0, 0, 0);
      }
    }
#pragma unroll
    for (int ct4 = 0; ct4 < 4; ct4++) {
      int ct = ch * 4 + ct4;
      float bv = b1[ct * 16 + li];
#pragma unroll
      for (int r = 0; r < 4; r++) {
        int row = 16 * wg + lg * 4 + r;
        *(ushort*)((char*)H1 + swz(row, (ct * 16 + li) * 2)) =
            f2bf(fmaxf(acc[ct4][r] + bv, 0.f));
      }
    }
  }
  __syncthreads();
  // ---- Phase C: h2 = relu(H1 @ W2 + b2) -> staged LDS + partial stats ----
  float ss[4] = {0, 0, 0, 0}, sq[4] = {0, 0, 0, 0};
  {
    f32x4 acc[4] = {};
    short8 af[4];
#pragma unroll
    for (int ks = 0; ks < 4; ks++)
      af[ks] = *(const short8*)((char*)H1 + swz(16 * wg + li, ks * 64 + lg * 16));
#pragma unroll
    for (int ct4 = 0; ct4 < 4; ct4++) {
      int ct = ch * 4 + ct4;
      const char* wp = (const char*)W2T + (ct * 16 + li) * 256 + lg * 16;
#pragma unroll
      for (int ks = 0; ks < 4; ks++) {
        short8 bf = *(const short8*)(wp + ks * 64);
        acc[ct4] = __builtin_amdgcn_mfma_f32_16x16x32_bf16(af[ks], bf, acc[ct4], 0, 0, 0);
      }
    }
#pragma unroll
    for (int ct4 = 0; ct4 < 4; ct4++) {
      int ct = ch * 4 + ct4;
      float bv = b2[ct * 16 + li];
#pragma unroll
      for (int r = 0; r < 4; r++) {
        int row = 16 * wg + lg * 4 + r;
        float v = fmaxf(acc[ct4][r] + bv, 0.f);
        *(ushort*)((char*)As + swz(row, (ct * 16 + li) * 2)) = f2bf(v);
        float vm = (row0 + row < N_NODES) ? v : 0.f;
        ss[ct4] += vm;
        sq[ct4] += vm * vm;
      }
    }
  }
#pragma unroll
  for (int ct4 = 0; ct4 < 4; ct4++) {
    ss[ct4] += __shfl_xor(ss[ct4], 16, 64);
    ss[ct4] += __shfl_xor(ss[ct4], 32, 64);
    sq[ct4] += __shfl_xor(sq[ct4], 16, 64);
    sq[ct4] += __shfl_xor(sq[ct4], 32, 64);
  }
  if (l < 16) {
#pragma unroll
    for (int ct4 = 0; ct4 < 4; ct4++) {
      sums[w4 * DIM + (ch * 4 + ct4) * 16 + l] = ss[ct4];
      sqs[w4 * DIM + (ch * 4 + ct4) * 16 + l] = sq[ct4];
      sums[w4 * DIM + ((1 - ch) * 4 + ct4) * 16 + l] = 0.f;
      sqs[w4 * DIM + ((1 - ch) * 4 + ct4) * 16 + l] = 0.f;
    }
  }
  __syncthreads();
  // coalesced copy-out of staged h2
  for (int t = tid; t < 512; t += 256) {
    int row = t >> 4, chunk = t & 15;
    int grow = row0 + row;
    if (grow < N_NODES) {
      short8 v = *(const short8*)((char*)As + swz(row, chunk * 16));
      *(short8*)(out + (size_t)grow * DIM + chunk * 8) = v;
    }
  }
  if (tid < DIM) {
    float t1 = 0.f, t2 = 0.f;
#pragma unroll
    for (int g = 0; g < 4; g++) {
      t1 += sums[g * DIM + tid];
      t2 += sqs[g * DIM + tid];
    }
    bstat[(size_t)blockIdx.x * DIM + tid] = t1;
    bstat[((size_t)NBLK32 + blockIdx.x) * DIM + tid] = t2;
  }
}

// ---------------- stats reduce: 256 cols (sum | sumsq), shuffle-reduce ------

__global__ __launch_bounds__(64) void stats_reduce_kernel(
    const float* __restrict__ bstat, float* __restrict__ stats) {
  int c = blockIdx.x;  // 0..127 -> col sums; 128..255 -> col sumsqs
  int t = threadIdx.x;
  const float* src = bstat + (c < DIM ? 0 : (size_t)NBLK32 * DIM) + (c & (DIM - 1));
  float a = 0.f;
  for (int b = t; b < NBLK32; b += 64) a += src[(size_t)b * DIM];
#pragma unroll
  for (int m = 32; m >= 1; m >>= 1) a += __shfl_xor(a, m, 64);
  if (t == 0) stats[c] = a;
}

// ---------------- pooling: one block per graph, contiguous rows, no atomics -

__global__ __launch_bounds__(128) void pool2_kernel(const ushort* __restrict__ h,
    const int* __restrict__ gstart, float* __restrict__ pool) {
  int g = blockIdx.x, t = threadIdx.x;
  int s = gstart[g], e = gstart[g + 1];
  float a0 = 0.f, a1 = 0.f, a2 = 0.f, a3 = 0.f;
  int i = s;
  for (; i + 3 < e; i += 4) {
    a0 += bf2f((short)h[(size_t)(i + 0) * DIM + t]);
    a1 += bf2f((short)h[(size_t)(i + 1) * DIM + t]);
    a2 += bf2f((short)h[(size_t)(i + 2) * DIM + t]);
    a3 += bf2f((short)h[(size_t)(i + 3) * DIM + t]);
  }
  for (; i < e; i++) a0 += bf2f((short)h[(size_t)i * DIM + t]);
  float cn = (float)(e - s);
  if (cn < 1.f) cn = 1.f;
  pool[g * DIM + t] = ((a0 + a1) + (a2 + a3)) / cn;
}

// ---------------- final: BN affine (layer 3) + MLP + log_softmax -----------

__global__ __launch_bounds__(128) void final_kernel(const float* __restrict__ pool,
    const float* __restrict__ stats3,
    const float* __restrict__ gamma3, const float* __restrict__ beta3,
    const float* __restrict__ lw1, const float* __restrict__ lb1,
    const float* __restrict__ lw2, const float* __restrict__ lb2,
    float* __restrict__ out) {
  int g = blockIdx.x, t = threadIdx.x;
  __shared__ float p[DIM];
  __shared__ float part[2];
  __shared__ float z2[N_CLS];
  const float invN = 1.0f / N_NODES;
  float mu = stats3[t] * invN;
  float var = fmaxf(stats3[DIM + t] * invN - mu * mu, 0.f);
  float sc = gamma3[t] * rsqrtf(var + BN_EPSV);
  float sh = beta3[t] - mu * sc;
  p[t] = sc * pool[g * DIM + t] + sh;
  __syncthreads();
  float acc = lb1[t];
  for (int k = 0; k < DIM; k++) acc += p[k] * lw1[k * DIM + t];
  acc = fmaxf(acc, 0.f);
  for (int c = 0; c < N_CLS; c++) {
    float v = acc * lw2[t * N_CLS + c];
#pragma unroll
    for (int m = 32; m >= 1; m >>= 1) v += __shfl_xor(v, m, 64);
    if ((t & 63) == 0) part[t >> 6] = v;
    __syncthreads();
    if (t == 0) z2[c] = part[0] + part[1] + lb2[c];
    __syncthreads();
  }
  if (t == 0) {
    float mx = -1e30f;
    for (int c = 0; c < N_CLS; c++) mx = fmaxf(mx, z2[c]);
    float sum = 0.f;
    for (int c = 0; c < N_CLS; c++) sum += expf(z2[c] - mx);
    float lse = mx + logf(sum);
    for (int c = 0; c < N_CLS; c++) out[g * N_CLS + c] = z2[c] - lse;
  }
}

// ---------------- launch ----------------

extern "C" void kernel_launch(void* const* d_in, const int* in_sizes, int n_in,
                              void* d_out, int out_size, void* d_ws, size_t ws_size,
                              hipStream_t stream) {
  const float* x = (const float*)d_in[0];
  const int* edge = (const int*)d_in[1];
  const int* batch = (const int*)d_in[2];
  const float *w[3][2], *bv[3][2], *gam[3], *bet[3];
  int idx = 3;
  for (int l = 0; l < 3; l++) {
    w[l][0] = (const float*)d_in[idx++]; bv[l][0] = (const float*)d_in[idx++];
    w[l][1] = (const float*)d_in[idx++]; bv[l][1] = (const float*)d_in[idx++];
    gam[l] = (const float*)d_in[idx++];  bet[l] = (const float*)d_in[idx++];
  }
  const float* eps = (const float*)d_in[idx++];
  const float* lw1 = (const float*)d_in[idx++];
  const float* lb1 = (const float*)d_in[idx++];
  const float* lw2 = (const float*)d_in[idx++];
  const float* lb2 = (const float*)d_in[idx++];

  char* ws = (char*)d_ws;
  size_t off_b = 0;
  auto alloc = [&](size_t b) -> char* {
    char* p = ws + off_b;
    off_b += (b + 255) & ~(size_t)255;
    return p;
  };
  int* cnt = (int*)alloc((size_t)N_NODES * 4);
  ushort* csr = (ushort*)alloc((size_t)N_NODES * CAP * 2);
  ushort* P0 = (ushort*)alloc((size_t)(N_NODES + 1) * DIM * 2);  // xb / h layers
  ushort* P1 = (ushort*)alloc((size_t)(N_NODES + 1) * DIM * 2);
  ushort* wt = (ushort*)alloc((size_t)6 * 16384 * 2);
  float* stats = (float*)alloc(3 * 2 * DIM * 4);
  float* pool = (float*)alloc((size_t)N_GRAPHS * DIM * 4);
  int* gstart = (int*)alloc((size_t)(N_GRAPHS + 1) * 4);
  float* bstat = (float*)alloc((size_t)2 * NBLK32 * DIM * 4);

  const int* srcp = edge;
  const int* dstp = edge + N_EDGES;
  // prep: cvt_w (384) | cvt_x (2048) | bounds+cnt0 (196) | zero-rows (1)
  prep_kernel<<<384 + 2048 + 196 + 1, 256, 0, stream>>>(
      x, P0, w[0][0], w[0][1], w[1][0], w[1][1], w[2][0], w[2][1], wt,
      batch, gstart, cnt, P0, P1);
  fill_kernel<<<2048, 256, 0, stream>>>(srcp, dstp, cnt, csr);

  // L1: layer(P0)->P1
  layer_kernel<true><<<NBLK32, 256, 0, stream>>>(
      P0, cnt, csr, nullptr, nullptr, nullptr, eps, 0,
      wt + 0 * 16384, bv[0][0], wt + 1 * 16384, bv[0][1], P1, bstat);
  stats_reduce_kernel<<<256, 64, 0, stream>>>(bstat, stats);
  // L2: layer(P1, fold s0)->P0
  layer_kernel<false><<<NBLK32, 256, 0, stream>>>(
      P1, cnt, csr, stats, gam[0], bet[0], eps, 1,
      wt + 2 * 16384, bv[1][0], wt + 3 * 16384, bv[1][1], P0, bstat);
  stats_reduce_kernel<<<256, 64, 0, stream>>>(bstat, stats + 2 * DIM);
  // L3: layer(P0, fold s1)->P1
  layer_kernel<false><<<NBLK32, 256, 0, stream>>>(
      P0, cnt, csr, stats + 2 * DIM, gam[1], bet[1], eps, 2,
      wt + 4 * 16384, bv[2][0], wt + 5 * 16384, bv[2][1], P1, bstat);
  stats_reduce_kernel<<<256, 64, 0, stream>>>(bstat, stats + 4 * DIM);

  pool2_kernel<<<N_GRAPHS, 128, 0, stream>>>(P1, gstart, pool);
  final_kernel<<<N_GRAPHS, 128, 0, stream>>>(pool, stats + 4 * DIM,
                                             gam[2], bet[2], lw1, lb1, lw2, lb2,
                                             (float*)d_out);
}